// Round 1
// baseline (313.988 us; speedup 1.0000x reference)
//
#include <hip/hip_runtime.h>
#include <math.h>

#define B_ 8
#define N_ 256
#define F_ 512
#define H_ 256

// ---------------------------------------------------------------------------
// GEMM: out = act(A @ W + bias)
// A: [M,K] row-major, W: [K,N] row-major, bias: [N] or nullptr, relu flag.
// 64x64 tile, BK=16, 256 threads, 4x4 micro-tile per thread. fp32 (no fp32
// MFMA on CDNA4 -> vector ALU).
// ---------------------------------------------------------------------------
__global__ __launch_bounds__(256) void gemm_bias_act(
    const float* __restrict__ A, const float* __restrict__ W,
    const float* __restrict__ bias, float* __restrict__ out,
    int M, int N, int K, int relu)
{
    __shared__ float As[16][68];  // [BK][BM+4] pad -> 2-way max on staging stores
    __shared__ float Bs[16][64];  // [BK][BN]

    const int tid = threadIdx.x;
    const int bm = blockIdx.y * 64;
    const int bn = blockIdx.x * 64;
    const int tx = tid & 15;       // output col group
    const int ty = tid >> 4;       // output row group
    const int arow = tid >> 2;           // 0..63
    const int acol = (tid & 3) << 2;     // 0,4,8,12
    const int brow = tid >> 4;           // 0..15
    const int bcol = (tid & 15) << 2;    // 0..60

    float acc[4][4] = {};

    for (int k0 = 0; k0 < K; k0 += 16) {
        float4 av = *(const float4*)(A + (size_t)(bm + arow) * K + k0 + acol);
        float4 bv = *(const float4*)(W + (size_t)(k0 + brow) * N + bn + bcol);
        __syncthreads();   // previous iteration's reads complete
        As[acol + 0][arow] = av.x;
        As[acol + 1][arow] = av.y;
        As[acol + 2][arow] = av.z;
        As[acol + 3][arow] = av.w;
        *(float4*)(&Bs[brow][bcol]) = bv;
        __syncthreads();
#pragma unroll
        for (int k = 0; k < 16; ++k) {
            float a[4], b[4];
#pragma unroll
            for (int i = 0; i < 4; ++i) a[i] = As[k][ty * 4 + i];
#pragma unroll
            for (int j = 0; j < 4; ++j) b[j] = Bs[k][tx * 4 + j];
#pragma unroll
            for (int i = 0; i < 4; ++i)
#pragma unroll
                for (int j = 0; j < 4; ++j)
                    acc[i][j] = fmaf(a[i], b[j], acc[i][j]);
        }
    }

    const int row0 = bm + ty * 4;
    const int col0 = bn + tx * 4;
    float bvals[4] = {0.f, 0.f, 0.f, 0.f};
    if (bias) {
#pragma unroll
        for (int j = 0; j < 4; ++j) bvals[j] = bias[col0 + j];
    }
#pragma unroll
    for (int i = 0; i < 4; ++i) {
        float4 v;
        float t0 = acc[i][0] + bvals[0];
        float t1 = acc[i][1] + bvals[1];
        float t2 = acc[i][2] + bvals[2];
        float t3 = acc[i][3] + bvals[3];
        if (relu) {
            t0 = fmaxf(t0, 0.f); t1 = fmaxf(t1, 0.f);
            t2 = fmaxf(t2, 0.f); t3 = fmaxf(t3, 0.f);
        }
        v.x = t0; v.y = t1; v.z = t2; v.w = t3;
        *(float4*)(out + (size_t)(row0 + i) * N + col0) = v;
    }
}

// ---------------------------------------------------------------------------
// Pair-score core: out[b,i,j] = sigmoid( sum_h relu(a[b,i,h]+c[b,j,h])*W2[h] + b2 )
// (b1 already folded into c's GEMM bias.)  One block = one (b, 16x16 ij-tile).
// ---------------------------------------------------------------------------
__global__ __launch_bounds__(256) void pair_score(
    const float* __restrict__ Arow, const float* __restrict__ Crow,
    const float* __restrict__ W2, const float* __restrict__ b2p,
    float* __restrict__ out)
{
    __shared__ float aS[16][H_ + 1];   // stride 257 -> banks spread
    __shared__ float cS[16][H_ + 1];
    __shared__ float w2S[H_];

    const int tid = threadIdx.x;
    const int b  = blockIdx.z;
    const int i0 = blockIdx.y * 16;
    const int j0 = blockIdx.x * 16;

    const float* Ab = Arow + ((size_t)b * N_ + i0) * H_;
    const float* Cb = Crow + ((size_t)b * N_ + j0) * H_;

    for (int idx = tid; idx < 16 * H_; idx += 256) {
        int r = idx >> 8;
        int h = idx & (H_ - 1);
        aS[r][h] = Ab[(size_t)r * H_ + h];
        cS[r][h] = Cb[(size_t)r * H_ + h];
    }
    w2S[tid] = W2[tid];
    __syncthreads();

    const int tj = tid & 15;
    const int ti = tid >> 4;
    float s = 0.f;
#pragma unroll 8
    for (int h = 0; h < H_; ++h) {
        s = fmaf(fmaxf(aS[ti][h] + cS[tj][h], 0.f), w2S[h], s);
    }
    s += b2p[0];
    out[((size_t)b * N_ + i0 + ti) * N_ + j0 + tj] = 1.f / (1.f + expf(-s));
}

// ---------------------------------------------------------------------------
// stability = mean_b,i,j |c[b] - c[b-1 mod B]| ; consistency = mean_ij std_b (ddof=1)
// ---------------------------------------------------------------------------
__global__ __launch_bounds__(256) void invariance_partial(
    const float* __restrict__ causal, float* __restrict__ accum)
{
    const int idx = blockIdx.x * 256 + threadIdx.x;  // 0..N*N-1
    float x[B_];
#pragma unroll
    for (int b = 0; b < B_; ++b) x[b] = causal[(size_t)b * (N_ * N_) + idx];

    float stab = 0.f, mean = 0.f;
#pragma unroll
    for (int b = 0; b < B_; ++b) {
        stab += fabsf(x[b] - x[(b + B_ - 1) % B_]);
        mean += x[b];
    }
    mean *= (1.f / B_);
    float var = 0.f;
#pragma unroll
    for (int b = 0; b < B_; ++b) {
        float d = x[b] - mean;
        var = fmaf(d, d, var);
    }
    float sd = sqrtf(var * (1.f / (B_ - 1)));

#pragma unroll
    for (int off = 32; off > 0; off >>= 1) {
        stab += __shfl_down(stab, off, 64);
        sd   += __shfl_down(sd, off, 64);
    }
    if ((threadIdx.x & 63) == 0) {
        atomicAdd(&accum[0], stab);
        atomicAdd(&accum[1], sd);
    }
}

__global__ void finalize_kernel(const float* __restrict__ accum,
                                float* __restrict__ out_scalar)
{
    float stability   = accum[0] * (1.f / (float)(B_ * N_ * N_));
    float consistency = accum[1] * (1.f / (float)(N_ * N_));
    out_scalar[0] = 1.f - (stability + consistency) * 0.5f;
}

// ---------------------------------------------------------------------------
extern "C" void kernel_launch(void* const* d_in, const int* in_sizes, int n_in,
                              void* d_out, int out_size, void* d_ws, size_t ws_size,
                              hipStream_t stream)
{
    const float* img   = (const float*)d_in[0];
    const float* txt   = (const float*)d_in[1];
    const float* ftW1  = (const float*)d_in[2];
    const float* ftb1  = (const float*)d_in[3];
    const float* ftW2  = (const float*)d_in[4];
    const float* ftb2  = (const float*)d_in[5];
    const float* slW1a = (const float*)d_in[6];
    const float* slW1b = (const float*)d_in[7];
    const float* slb1  = (const float*)d_in[8];
    const float* slW2  = (const float*)d_in[9];
    const float* slb2  = (const float*)d_in[10];
    const float* cnW1a = (const float*)d_in[11];
    const float* cnW1b = (const float*)d_in[12];
    const float* cnb1  = (const float*)d_in[13];
    const float* cnW2  = (const float*)d_in[14];
    const float* cnb2  = (const float*)d_in[15];

    float* out = (float*)d_out;
    float* structure = out;                               // [B,N,N]
    float* causal    = out + (size_t)B_ * N_ * N_;        // [B,N,N]
    float* inv       = out + 2 * (size_t)B_ * N_ * N_;    // scalar

    float* ws = (float*)d_ws;
    const size_t SZ = (size_t)B_ * N_ * H_;  // 524288
    float* buf0  = ws;            // h1 / a / a2
    float* buf1  = ws + SZ;       // img_h
    float* buf2  = ws + 2 * SZ;   // txt_h
    float* buf3  = ws + 3 * SZ;   // c / c2
    float* accum = ws + 4 * SZ;   // 2 floats

    hipMemsetAsync(accum, 0, 2 * sizeof(float), stream);

    const int M = B_ * N_;
    dim3 blk(256);
    dim3 ggrid(H_ / 64, M / 64);   // (4, 32)

    // feature transform: image
    gemm_bias_act<<<ggrid, blk, 0, stream>>>(img,  ftW1, ftb1, buf0, M, H_, F_, 1);
    gemm_bias_act<<<ggrid, blk, 0, stream>>>(buf0, ftW2, ftb2, buf1, M, H_, H_, 0);
    // feature transform: text
    gemm_bias_act<<<ggrid, blk, 0, stream>>>(txt,  ftW1, ftb1, buf0, M, H_, F_, 1);
    gemm_bias_act<<<ggrid, blk, 0, stream>>>(buf0, ftW2, ftb2, buf2, M, H_, H_, 0);
    // structure-learning projections: a = img_h@W1a ; c = txt_h@W1b + b1
    gemm_bias_act<<<ggrid, blk, 0, stream>>>(buf1, slW1a, nullptr, buf0, M, H_, H_, 0);
    gemm_bias_act<<<ggrid, blk, 0, stream>>>(buf2, slW1b, slb1,    buf3, M, H_, H_, 0);
    // structure = pair_scores(a, c)
    dim3 pgrid(N_ / 16, N_ / 16, B_);
    pair_score<<<pgrid, blk, 0, stream>>>(buf0, buf3, slW2, slb2, structure);
    // causal projections from structure
    gemm_bias_act<<<ggrid, blk, 0, stream>>>(structure, cnW1a, nullptr, buf0, M, H_, H_, 0);
    gemm_bias_act<<<ggrid, blk, 0, stream>>>(structure, cnW1b, cnb1,    buf3, M, H_, H_, 0);
    // causal = pair_scores(a2, c2)
    pair_score<<<pgrid, blk, 0, stream>>>(buf0, buf3, cnW2, cnb2, causal);
    // invariance
    invariance_partial<<<dim3(N_ * N_ / 256), blk, 0, stream>>>(causal, accum);
    finalize_kernel<<<dim3(1), dim3(1), 0, stream>>>(accum, inv);
}

// Round 2
// 191.881 us; speedup vs baseline: 1.6364x; 1.6364x over previous
//
#include <hip/hip_runtime.h>
#include <math.h>

#define B_ 8
#define N_ 256
#define F_ 512
#define H_ 256

typedef __attribute__((ext_vector_type(8))) short short8;
typedef __attribute__((ext_vector_type(4))) float floatx4;

__device__ __forceinline__ unsigned int f2bf_bits(float f) {
    unsigned int u = __float_as_uint(f);
    return (u + 0x7fffu + ((u >> 16) & 1u)) >> 16;   // RNE
}
__device__ __forceinline__ unsigned int pack2bf(float a, float b) {
    return f2bf_bits(a) | (f2bf_bits(b) << 16);
}
__device__ __forceinline__ float bf_lo(unsigned int u) { return __uint_as_float(u << 16); }
__device__ __forceinline__ float bf_hi(unsigned int u) { return __uint_as_float(u & 0xffff0000u); }

// ---------------------------------------------------------------------------
// Weight prep: fp32 W[K][256] -> bf16 W^T[256][K] so GEMM B-staging is
// contiguous 16B loads. 6 matrices in one dispatch.
// wt layout (ushort offsets): ftW1t 0 (256x512), ftW2t 131072, slW1at 196608,
// slW1bt 262144, cnW1at 327680, cnW1bt 393216. Total 458752.
// ---------------------------------------------------------------------------
__global__ __launch_bounds__(256) void prep_weights(
    const float* __restrict__ ftW1, const float* __restrict__ ftW2,
    const float* __restrict__ slW1a, const float* __restrict__ slW1b,
    const float* __restrict__ cnW1a, const float* __restrict__ cnW1b,
    unsigned short* __restrict__ wt)
{
    int t = blockIdx.x * 256 + threadIdx.x;   // 57344 threads, 8 outputs each
    const float* src; int K; unsigned short* dst;
    if (t < 16384) { src = ftW1; K = 512; dst = wt; }
    else {
        int m  = (t - 16384) >> 13;
        int lt = (t - 16384) & 8191;
        t = lt; K = 256;
        switch (m) {
            case 0:  src = ftW2;  dst = wt + 131072; break;
            case 1:  src = slW1a; dst = wt + 196608; break;
            case 2:  src = slW1b; dst = wt + 262144; break;
            case 3:  src = cnW1a; dst = wt + 327680; break;
            default: src = cnW1b; dst = wt + 393216; break;
        }
    }
    const int n  = t & 255;
    const int k0 = (t >> 8) * 8;
    unsigned int p[4];
#pragma unroll
    for (int j = 0; j < 4; ++j) {
        // lanes have consecutive n -> each of these global reads is coalesced
        float f0 = src[(size_t)(k0 + 2 * j)     * 256 + n];
        float f1 = src[(size_t)(k0 + 2 * j + 1) * 256 + n];
        p[j] = pack2bf(f0, f1);
    }
    *(uint4*)(dst + (size_t)n * K + k0) = make_uint4(p[0], p[1], p[2], p[3]);
}

// ---------------------------------------------------------------------------
// bf16 MFMA GEMM: out = act(A @ W + bias). 64x64 tile, BK=32, 256 thr (4 waves),
// wave w -> cols [16w,16w+16), 4 stacked 16x16x32 mfma per K-step.
// A: fp32 or bf16 (aBf16), converted/staged to LDS. W: prepped bf16 W^T.
// Fusion: A row-half split (aSplitBlk), W row-half split (wRowSplitBlk) or
// W col-half split (wColSplitBlk) with per-half bias.
// ---------------------------------------------------------------------------
__global__ __launch_bounds__(256) void gemm_mfma(
    const void* __restrict__ A0, const void* __restrict__ A1, int aSplitBlk, int aBf16,
    const unsigned short* __restrict__ Wt0, const unsigned short* __restrict__ Wt1,
    const float* __restrict__ bias0, const float* __restrict__ bias1,
    int wRowSplitBlk, int wColSplitBlk,
    void* __restrict__ out, int outBf16, int ldOut, int K, int relu)
{
    __shared__ unsigned short As[64][40];   // [row][k], pad 32->40 (16B-aligned rows)
    __shared__ unsigned short Bs[64][40];   // [col][k] from W^T

    const int tid = threadIdx.x;
    const int bx = blockIdx.x, by = blockIdx.y;

    const void* Abase; int arow0;
    if (by < aSplitBlk) { Abase = A0; arow0 = by * 64; }
    else                { Abase = A1; arow0 = (by - aSplitBlk) * 64; }

    int wcolBlk = bx;
    bool second;
    if (wColSplitBlk > 0) {
        second = (bx >= wColSplitBlk);
        if (second) wcolBlk = bx - wColSplitBlk;
    } else {
        second = (by >= wRowSplitBlk);
    }
    const unsigned short* Wt = second ? Wt1 : Wt0;
    const float* bias        = second ? bias1 : bias0;
    const int wcol = wcolBlk * 64;

    const int r    = tid >> 2;          // 0..63 staging row (A) / col (B)
    const int kq   = (tid & 3) * 8;     // k offset within BK
    const int lane = tid & 63;
    const int wv   = tid >> 6;          // wave id 0..3
    const int col  = lane & 15;
    const int quad = lane >> 4;

    floatx4 acc[4] = {};

    for (int k0 = 0; k0 < K; k0 += 32) {
        uint4 apack, bpack;
        if (aBf16) {
            apack = *(const uint4*)((const unsigned short*)Abase +
                                    (size_t)(arow0 + r) * K + k0 + kq);
        } else {
            const float* Af = (const float*)Abase + (size_t)(arow0 + r) * K + k0 + kq;
            float4 f0 = *(const float4*)Af;
            float4 f1 = *(const float4*)(Af + 4);
            apack.x = pack2bf(f0.x, f0.y); apack.y = pack2bf(f0.z, f0.w);
            apack.z = pack2bf(f1.x, f1.y); apack.w = pack2bf(f1.z, f1.w);
        }
        bpack = *(const uint4*)(Wt + (size_t)(wcol + r) * K + k0 + kq);
        __syncthreads();                 // previous iteration's LDS reads done
        *(uint4*)&As[r][kq] = apack;
        *(uint4*)&Bs[r][kq] = bpack;
        __syncthreads();

        short8 bfrag = *(const short8*)&Bs[wv * 16 + col][quad * 8];
#pragma unroll
        for (int tm = 0; tm < 4; ++tm) {
            short8 afrag = *(const short8*)&As[tm * 16 + col][quad * 8];
            acc[tm] = __builtin_amdgcn_mfma_f32_16x16x32_bf16(afrag, bfrag, acc[tm], 0, 0, 0);
        }
    }

    // D layout: col = lane&15, row = quad*4 + reg  [m89]
    const int ocol = bx * 64 + wv * 16 + col;
    const int bcol = wcol + wv * 16 + col;
    const float bv = bias ? bias[bcol] : 0.f;
#pragma unroll
    for (int tm = 0; tm < 4; ++tm) {
#pragma unroll
        for (int rr = 0; rr < 4; ++rr) {
            float v = acc[tm][rr] + bv;
            if (relu) v = fmaxf(v, 0.f);
            const size_t o = (size_t)(by * 64 + tm * 16 + quad * 4 + rr) * ldOut + ocol;
            if (outBf16) ((unsigned short*)out)[o] = (unsigned short)f2bf_bits(v);
            else         ((float*)out)[o] = v;
        }
    }
}

// ---------------------------------------------------------------------------
// Pair-score: out[b,i,j] = sigmoid( sum_h relu(a[b,i,h]+c[b,j,h])*W2[h] + b2 )
// a, c are bf16 with row strides ldA/ldC. 32x32 tile/block, 2x2 per thread,
// h unrolled x4 (b64 LDS reads). Chunk-XOR swizzle: logical 8-col chunk ch of
// row r lives at chunk ch ^ ((r>>1)&7)  -> c-row reads spread over 8 banks
// (2-way = free), and row pairs (2t, 2t+1) share the same key.
// ---------------------------------------------------------------------------
__global__ __launch_bounds__(256) void pair_score(
    const unsigned short* __restrict__ Abase, int ldA,
    const unsigned short* __restrict__ Cbase, int ldC,
    const float* __restrict__ W2, const float* __restrict__ b2p,
    float* __restrict__ out)
{
    __shared__ unsigned short aS[32][256];
    __shared__ unsigned short cS[32][256];
    __shared__ float w2S[H_];

    const int tid = threadIdx.x;
    const int b   = blockIdx.z;
    const int i0b = blockIdx.y * 32;
    const int j0b = blockIdx.x * 32;

    {
        const int r   = tid >> 3;        // 0..31
        const int c8  = tid & 7;
        const int key = (r >> 1) & 7;
        const unsigned short* Ar = Abase + ((size_t)b * N_ + i0b + r) * ldA;
        const unsigned short* Cr = Cbase + ((size_t)b * N_ + j0b + r) * ldC;
#pragma unroll
        for (int rep = 0; rep < 4; ++rep) {
            const int ch = c8 + rep * 8;                 // 0..31
            uint4 va = *(const uint4*)(Ar + ch * 8);
            uint4 vc = *(const uint4*)(Cr + ch * 8);
            const int pc = (ch ^ key) << 3;
            *(uint4*)&aS[r][pc] = va;
            *(uint4*)&cS[r][pc] = vc;
        }
        w2S[tid] = W2[tid];
    }
    __syncthreads();

    const int ti = tid >> 4, tj = tid & 15;
    const int ia = ti * 2, jc = tj * 2;
    const int keyA = ti & 7, keyC = tj & 7;

    float s00 = 0.f, s01 = 0.f, s10 = 0.f, s11 = 0.f;
#pragma unroll 4
    for (int h = 0; h < H_; h += 4) {
        const int chunk = h >> 3, sub = h & 7;
        const int pa = ((chunk ^ keyA) << 3) | sub;
        const int pc = ((chunk ^ keyC) << 3) | sub;
        uint2 ua0 = *(const uint2*)&aS[ia][pa];
        uint2 ua1 = *(const uint2*)&aS[ia + 1][pa];
        uint2 uc0 = *(const uint2*)&cS[jc][pc];
        uint2 uc1 = *(const uint2*)&cS[jc + 1][pc];
        float4 w  = *(const float4*)&w2S[h];
        float a0[4] = { bf_lo(ua0.x), bf_hi(ua0.x), bf_lo(ua0.y), bf_hi(ua0.y) };
        float a1[4] = { bf_lo(ua1.x), bf_hi(ua1.x), bf_lo(ua1.y), bf_hi(ua1.y) };
        float c0[4] = { bf_lo(uc0.x), bf_hi(uc0.x), bf_lo(uc0.y), bf_hi(uc0.y) };
        float c1[4] = { bf_lo(uc1.x), bf_hi(uc1.x), bf_lo(uc1.y), bf_hi(uc1.y) };
        float wv[4] = { w.x, w.y, w.z, w.w };
#pragma unroll
        for (int q = 0; q < 4; ++q) {
            s00 = fmaf(fmaxf(a0[q] + c0[q], 0.f), wv[q], s00);
            s01 = fmaf(fmaxf(a0[q] + c1[q], 0.f), wv[q], s01);
            s10 = fmaf(fmaxf(a1[q] + c0[q], 0.f), wv[q], s10);
            s11 = fmaf(fmaxf(a1[q] + c1[q], 0.f), wv[q], s11);
        }
    }
    const float bb = b2p[0];
    const size_t ob = ((size_t)b * N_ + i0b + ia) * N_ + j0b + jc;
    out[ob]           = 1.f / (1.f + expf(-(s00 + bb)));
    out[ob + 1]       = 1.f / (1.f + expf(-(s01 + bb)));
    out[ob + N_]      = 1.f / (1.f + expf(-(s10 + bb)));
    out[ob + N_ + 1]  = 1.f / (1.f + expf(-(s11 + bb)));
}

// ---------------------------------------------------------------------------
__global__ __launch_bounds__(256) void invariance_partial(
    const float* __restrict__ causal, float* __restrict__ accum)
{
    const int idx = blockIdx.x * 256 + threadIdx.x;  // 0..N*N-1
    float x[B_];
#pragma unroll
    for (int b = 0; b < B_; ++b) x[b] = causal[(size_t)b * (N_ * N_) + idx];

    float stab = 0.f, mean = 0.f;
#pragma unroll
    for (int b = 0; b < B_; ++b) {
        stab += fabsf(x[b] - x[(b + B_ - 1) % B_]);
        mean += x[b];
    }
    mean *= (1.f / B_);
    float var = 0.f;
#pragma unroll
    for (int b = 0; b < B_; ++b) {
        float d = x[b] - mean;
        var = fmaf(d, d, var);
    }
    float sd = sqrtf(var * (1.f / (B_ - 1)));

#pragma unroll
    for (int off = 32; off > 0; off >>= 1) {
        stab += __shfl_down(stab, off, 64);
        sd   += __shfl_down(sd, off, 64);
    }
    if ((threadIdx.x & 63) == 0) {
        atomicAdd(&accum[0], stab);
        atomicAdd(&accum[1], sd);
    }
}

__global__ void finalize_kernel(const float* __restrict__ accum,
                                float* __restrict__ out_scalar)
{
    float stability   = accum[0] * (1.f / (float)(B_ * N_ * N_));
    float consistency = accum[1] * (1.f / (float)(N_ * N_));
    out_scalar[0] = 1.f - (stability + consistency) * 0.5f;
}

// ---------------------------------------------------------------------------
extern "C" void kernel_launch(void* const* d_in, const int* in_sizes, int n_in,
                              void* d_out, int out_size, void* d_ws, size_t ws_size,
                              hipStream_t stream)
{
    const float* img   = (const float*)d_in[0];
    const float* txt   = (const float*)d_in[1];
    const float* ftW1  = (const float*)d_in[2];
    const float* ftb1  = (const float*)d_in[3];
    const float* ftW2  = (const float*)d_in[4];
    const float* ftb2  = (const float*)d_in[5];
    const float* slW1a = (const float*)d_in[6];
    const float* slW1b = (const float*)d_in[7];
    const float* slb1  = (const float*)d_in[8];
    const float* slW2  = (const float*)d_in[9];
    const float* slb2  = (const float*)d_in[10];
    const float* cnW1a = (const float*)d_in[11];
    const float* cnW1b = (const float*)d_in[12];
    const float* cnb1  = (const float*)d_in[13];
    const float* cnW2  = (const float*)d_in[14];
    const float* cnb2  = (const float*)d_in[15];

    float* out       = (float*)d_out;
    float* structure = out;                              // [B,N,N] fp32
    float* causal    = out + (size_t)B_ * N_ * N_;       // [B,N,N] fp32
    float* inv       = out + 2 * (size_t)B_ * N_ * N_;   // scalar

    unsigned short* wt   = (unsigned short*)d_ws;        // 458752 ushort (pad to 1MB)
    unsigned short* h1b  = wt + 524288;                  // [4096][256] bf16
    unsigned short* h12b = h1b + 1048576;                // [4096][256] bf16 (img_h;txt_h)
    unsigned short* acb  = h12b + 1048576;               // [4096][256] bf16 (a;c)
    unsigned short* ac2b = acb + 1048576;                // [2048][512] bf16 (a2|c2)
    float* accum         = (float*)(ac2b + 1048576);     // 2 floats

    hipMemsetAsync(accum, 0, 2 * sizeof(float), stream);

    dim3 blk(256);
    const int BIG = 1 << 20;

    prep_weights<<<dim3(224), blk, 0, stream>>>(ftW1, ftW2, slW1a, slW1b, cnW1a, cnW1b, wt);

    const unsigned short* wtFT1 = wt;
    const unsigned short* wtFT2 = wt + 131072;
    const unsigned short* wtSLA = wt + 196608;
    const unsigned short* wtSLB = wt + 262144;
    const unsigned short* wtCNA = wt + 327680;
    const unsigned short* wtCNB = wt + 393216;

    // G1: [img;txt](4096x512) @ ftW1 + b1, relu -> h1b (bf16)
    gemm_mfma<<<dim3(4, 64), blk, 0, stream>>>(
        img, txt, 32, 0, wtFT1, wtFT1, ftb1, ftb1, BIG, 0,
        h1b, 1, 256, 512, 1);
    // G2: h1 @ ftW2 + b2 -> h12b (img_h;txt_h)
    gemm_mfma<<<dim3(4, 64), blk, 0, stream>>>(
        h1b, h1b, BIG, 1, wtFT2, wtFT2, ftb2, ftb2, BIG, 0,
        h12b, 1, 256, 256, 0);
    // G3: rows 0..2047: img_h @ slW1a (no bias); rows 2048..: txt_h @ slW1b + slb1
    gemm_mfma<<<dim3(4, 64), blk, 0, stream>>>(
        h12b, h12b, BIG, 1, wtSLA, wtSLB, nullptr, slb1, 32, 0,
        acb, 1, 256, 256, 0);
    // P1: structure = pair(a, c)
    pair_score<<<dim3(8, 8, 8), blk, 0, stream>>>(
        acb, 256, acb + (size_t)2048 * 256, 256, slW2, slb2, structure);
    // G4: structure @ [cnW1a | cnW1b(+cnb1)] -> ac2b [2048][512]
    gemm_mfma<<<dim3(8, 32), blk, 0, stream>>>(
        structure, structure, BIG, 0, wtCNA, wtCNB, nullptr, cnb1, BIG, 4,
        ac2b, 1, 512, 256, 0);
    // P2: causal = pair(a2, c2)
    pair_score<<<dim3(8, 8, 8), blk, 0, stream>>>(
        ac2b, 512, ac2b + 256, 512, cnW2, cnb2, causal);
    // invariance
    invariance_partial<<<dim3(N_ * N_ / 256), blk, 0, stream>>>(causal, accum);
    finalize_kernel<<<dim3(1), dim3(1), 0, stream>>>(accum, inv);
}